// Round 12
// baseline (940.578 us; speedup 1.0000x reference)
//
#include <hip/hip_runtime.h>
#include <hip/hip_bf16.h>
#include <cstdint>
#include <cstddef>

// Problem constants
#define NB 64      // batch
#define NT 256     // time steps
#define NL 64      // links
#define NH 128     // hidden
#define NN 16384   // nodes = NB*NT
#define NE 524288  // edges
#define NG 512     // 4*NH gates
#define NOUT 768   // 12*NL

// ---------------- small prep kernels ----------------

// Wt[n][k] = W[k][n], W is [K, Nout] row-major
__global__ __launch_bounds__(256) void k_transpose(const float* __restrict__ W,
                                                   float* __restrict__ Wt,
                                                   int K, int Nout) {
  int i = blockIdx.x * 256 + threadIdx.x;
  if (i < K * Nout) {
    int k = i / Nout, n = i % Nout;
    Wt[n * K + k] = W[i];
  }
}

// dvec[j] = sum_m dist[m] * W0[(64+m)*128 + j]   (128 blocks, one per j)
__global__ __launch_bounds__(256) void k_dvec(const float* __restrict__ dist,
                                              const float* __restrict__ W0,
                                              float* __restrict__ dvec) {
  __shared__ float red[256];
  int j = blockIdx.x;
  int t = threadIdx.x;
  float acc = 0.f;
  for (int m = t; m < 4096; m += 256)
    acc += dist[m] * W0[(size_t)(64 + m) * 128 + j];
  red[t] = acc;
  __syncthreads();
  for (int off = 128; off > 0; off >>= 1) {
    if (t < off) red[t] += red[t + off];
    __syncthreads();
  }
  if (t == 0) dvec[j] = red[0];
}

__global__ __launch_bounds__(256) void k_count(const int* __restrict__ dst,
                                               int* __restrict__ counts) {
  int i = blockIdx.x * 256 + threadIdx.x;
  atomicAdd(&counts[dst[i]], 1);
}

// exclusive scan of counts[16384] -> rowstart[16385]; also emits dinv (fused)
__global__ __launch_bounds__(1024) void k_scan(const int* __restrict__ counts,
                                               int* __restrict__ rowstart,
                                               float* __restrict__ dinv) {
  __shared__ int part[1024];
  int t = threadIdx.x;
  int base = t * 16;
  int local[16];
  int s = 0;
#pragma unroll
  for (int i = 0; i < 16; i++) {
    int cv = counts[base + i];
    local[i] = s; s += cv;
    dinv[base + i] = rsqrtf((float)cv + 1.0f);
  }
  part[t] = s;
  __syncthreads();
  for (int off = 1; off < 1024; off <<= 1) {
    int v = (t >= off) ? part[t - off] : 0;
    __syncthreads();
    part[t] += v;
    __syncthreads();
  }
  int prefix = (t == 0) ? 0 : part[t - 1];
#pragma unroll
  for (int i = 0; i < 16; i++) rowstart[base + i] = prefix + local[i];
  if (t == 1023) rowstart[16384] = part[1023];
}

__global__ __launch_bounds__(256) void k_fill(const int* __restrict__ src,
                                              const int* __restrict__ dst,
                                              const int* __restrict__ rowstart,
                                              int* __restrict__ fill,
                                              const float* __restrict__ dinv,
                                              int2* __restrict__ csr) {
  int e = blockIdx.x * 256 + threadIdx.x;
  int sN = src[e], dN = dst[e];
  int pos = rowstart[dN] + atomicAdd(&fill[dN], 1);
  csr[pos] = make_int2(sN, __float_as_int(dinv[sN] * dinv[dN]));
}

// ---------------- bf16 weight pack for LSTM gates 0,1 (i,f) only ----------------
// Layout: out[c*512 + tid], c=0..7. gate g=c>>2 (0 or 1), quarter-pair q=c&3.
// Thread tid (u=tid>>2, c4=tid&3) consumes chunks for k-slices hidx[2q], hidx[2q+1],
// packed as 4 dwords of 2 bf16 each in h-order. (Same verified layout as R8/R9.)
__device__ __forceinline__ unsigned rne_bf16(float f) {
  unsigned u = __float_as_uint(f);
  return (u + 0x7FFFu + ((u >> 16) & 1u)) >> 16;
}

__global__ __launch_bounds__(256) void k_packw2(const float* __restrict__ Whh,
                                                uint4* __restrict__ out) {
  int idx = blockIdx.x * 256 + threadIdx.x;  // 0..4095
  int c = idx >> 9, tid = idx & 511;
  int u = tid >> 2, c4 = tid & 3;
  int g = c >> 2, q = c & 3;  // g in {0,1}
  int h0 = c4 * 8 + (((u & 7) + 2 * c4 + 2 * q) & 7);
  int h1 = c4 * 8 + (((u & 7) + 2 * c4 + 2 * q + 1) & 7);
  const float* row = Whh + (size_t)(g * 128 + u) * 128;
  const float* p0 = row + h0 * 4;
  const float* p1 = row + h1 * 4;
  uint4 o;
  o.x = rne_bf16(p0[0]) | (rne_bf16(p0[1]) << 16);
  o.y = rne_bf16(p0[2]) | (rne_bf16(p0[3]) << 16);
  o.z = rne_bf16(p1[0]) | (rne_bf16(p1[1]) << 16);
  o.w = rne_bf16(p1[2]) | (rne_bf16(p1[3]) << 16);
  out[c * 512 + tid] = o;
}

// ---------------- GEMM: C[M,Nn] = A[M,K] * B[Nn,K]^T (+bias0+bias1) ----------------
// XOR-swizzled float4 LDS groups (R11-verified). PERMC: gate-interleaved store.
template <int K, bool RELU, bool PERMC = false>
__global__ __launch_bounds__(256) void k_gemm_abt(const float* __restrict__ A,
                                                  const float* __restrict__ Bm,
                                                  const float* __restrict__ bias0,
                                                  const float* __restrict__ bias1,
                                                  float* __restrict__ C, int Nn) {
  __shared__ float As[64][K];
  __shared__ float Bs[64][K];
  const int tid = threadIdx.x;
  const int bm = blockIdx.x, bn = blockIdx.y;
  const int VPR = K / 4;  // float4 groups per row
  for (int i = tid; i < 64 * VPR; i += 256) {
    int r = i / VPR, c = i % VPR;
    int xr = (r >> 2) & 7;
    float4 q = *(const float4*)(A + (size_t)(bm * 64 + r) * K + c * 4);
    *(float4*)&As[r][(c ^ xr) * 4] = q;
  }
  for (int i = tid; i < 64 * VPR; i += 256) {
    int r = i / VPR, c = i % VPR;
    int xr = (r >> 2) & 7;
    float4 q = *(const float4*)(Bm + (size_t)(bn * 64 + r) * K + c * 4);
    *(float4*)&Bs[r][(c ^ xr) * 4] = q;
  }
  __syncthreads();
  const int tr = (tid >> 4) << 2;   // output rows tr..tr+3
  const int tc = (tid & 15) << 2;   // output cols tc..tc+3
  const int axor = (tr >> 2) & 7;
  const int bxor = (tc >> 2) & 7;
  float acc[4][4] = {};
#pragma unroll 2
  for (int k4 = 0; k4 < VPR; k4++) {
    int ka = (k4 ^ axor) * 4;
    int kb = (k4 ^ bxor) * 4;
    float4 a0 = *(const float4*)&As[tr + 0][ka];
    float4 a1 = *(const float4*)&As[tr + 1][ka];
    float4 a2 = *(const float4*)&As[tr + 2][ka];
    float4 a3 = *(const float4*)&As[tr + 3][ka];
    float4 b0 = *(const float4*)&Bs[tc + 0][kb];
    float4 b1 = *(const float4*)&Bs[tc + 1][kb];
    float4 b2 = *(const float4*)&Bs[tc + 2][kb];
    float4 b3 = *(const float4*)&Bs[tc + 3][kb];
#define DOT4(i2, j2, av, bv)                                                   \
    acc[i2][j2] = fmaf(av.x, bv.x, acc[i2][j2]);                               \
    acc[i2][j2] = fmaf(av.y, bv.y, acc[i2][j2]);                               \
    acc[i2][j2] = fmaf(av.z, bv.z, acc[i2][j2]);                               \
    acc[i2][j2] = fmaf(av.w, bv.w, acc[i2][j2]);
    DOT4(0, 0, a0, b0) DOT4(0, 1, a0, b1) DOT4(0, 2, a0, b2) DOT4(0, 3, a0, b3)
    DOT4(1, 0, a1, b0) DOT4(1, 1, a1, b1) DOT4(1, 2, a1, b2) DOT4(1, 3, a1, b3)
    DOT4(2, 0, a2, b0) DOT4(2, 1, a2, b1) DOT4(2, 2, a2, b2) DOT4(2, 3, a2, b3)
    DOT4(3, 0, a3, b0) DOT4(3, 1, a3, b1) DOT4(3, 2, a3, b2) DOT4(3, 3, a3, b3)
#undef DOT4
  }
#pragma unroll
  for (int i2 = 0; i2 < 4; i2++) {
    int row = bm * 64 + tr + i2;
#pragma unroll
    for (int j2 = 0; j2 < 4; j2++) {
      int col = bn * 64 + tc + j2;
      float v = acc[i2][j2];
      if (bias0) v += bias0[col];
      if (bias1) v += bias1[col];
      if (RELU) v = fmaxf(v, 0.f);
      int colw = PERMC ? ((col & 127) * 4 + (col >> 7)) : col;
      C[(size_t)row * Nn + colw] = v;
    }
  }
}

// ---------------- GCN aggregation (float2 lanes, packed CSR, 4-edge unroll) ---------
__global__ __launch_bounds__(256) void k_agg(const float* __restrict__ h,
                                             const int* __restrict__ rowstart,
                                             const int2* __restrict__ csr,
                                             const float* __restrict__ dinv,
                                             const float* __restrict__ bias,
                                             float* __restrict__ out) {
  int node = blockIdx.x * 4 + (threadIdx.x >> 6);
  int lane = threadIdx.x & 63;
  int s = rowstart[node], e = rowstart[node + 1];
  const float2* h2 = (const float2*)h;
  float ax = 0.f, ay = 0.f;
  int p = s;
  for (; p + 3 < e; p += 4) {
    int2 pk0 = csr[p];
    int2 pk1 = csr[p + 1];
    int2 pk2 = csr[p + 2];
    int2 pk3 = csr[p + 3];
    float2 hv0 = h2[(size_t)pk0.x * 64 + lane];
    float2 hv1 = h2[(size_t)pk1.x * 64 + lane];
    float2 hv2 = h2[(size_t)pk2.x * 64 + lane];
    float2 hv3 = h2[(size_t)pk3.x * 64 + lane];
    float w0 = __int_as_float(pk0.y);
    float w1 = __int_as_float(pk1.y);
    float w2 = __int_as_float(pk2.y);
    float w3 = __int_as_float(pk3.y);
    ax = fmaf(hv0.x, w0, ax); ay = fmaf(hv0.y, w0, ay);
    ax = fmaf(hv1.x, w1, ax); ay = fmaf(hv1.y, w1, ay);
    ax = fmaf(hv2.x, w2, ax); ay = fmaf(hv2.y, w2, ay);
    ax = fmaf(hv3.x, w3, ax); ay = fmaf(hv3.y, w3, ay);
  }
  for (; p < e; p++) {
    int2 pk0 = csr[p];
    float2 hv0 = h2[(size_t)pk0.x * 64 + lane];
    float w0 = __int_as_float(pk0.y);
    ax = fmaf(hv0.x, w0, ax); ay = fmaf(hv0.y, w0, ay);
  }
  float di = dinv[node];
  float sw = di * di;
  float2 hs = h2[(size_t)node * 64 + lane];
  float2 bv = ((const float2*)bias)[lane];
  ax = fmaf(hs.x, sw, ax) + bv.x;
  ay = fmaf(hs.y, sw, ay) + bv.y;
  float2 o;
  o.x = fmaxf(ax, 0.f);
  o.y = fmaxf(ay, 0.f);
  ((float2*)out)[(size_t)node * 64 + lane] = o;
}

// ---------------- LSTM recurrence v11: DUAL-PIPE weight delivery ----------
// Measured invariant: step time = weight-delivery time, single-pipe.
//   R7  (f32, scratch/L2 stream):  256 KB/step/CU @ ~128 B/cyc -> 2000 cyc, 213us/layer
//   R9  (bf16, LDS):               192 KB/step/CU @ ~60-90 B/cyc -> 344us/layer
// The two pipes (vmcnt VMEM vs lgkm LDS) are independent and both underused.
// v11 splits the weight set: gates 0,1 (i,f; sigmoid, slope<=0.25) as bf16 in
// LDS (64 KB, staged once, 128 B/thread/step); gates 2,3 (g,o; g is the tanh
// path, kept f32) via R7's named-register + in-loop-pin mechanism (compiler
// streams from scratch at the L2 rate, 256 B/thread/step ~ 1000 cyc).
// Expected: max(~1000 scratch, ~730 LDS, ~800 VALU) ~ 1200-1500 cyc/step.
// Numerics: strictly better than full-bf16 (R8/R9: absmax 1.95e-3 < 5.2e-3).

template <int CTRL>
__device__ __forceinline__ float dppadd(float x) {
  int r = __builtin_amdgcn_update_dpp(0, __float_as_int(x), CTRL, 0xF, 0xF, true);
  return x + __int_as_float(r);
}
// quad_perm[1,0,3,2] = 0xB1 (xor1), quad_perm[2,3,0,1] = 0x4E (xor2)

__device__ __forceinline__ float sigf(float x) {
  return 1.f / (1.f + __expf(-x));
}
__device__ __forceinline__ float tanhf_fast(float x) {
  return 1.f - 2.f / (__expf(2.f * x) + 1.f);
}

typedef float f2v __attribute__((ext_vector_type(2)));
typedef float f4v __attribute__((ext_vector_type(4)));

__device__ __forceinline__ f2v unpk(unsigned d) {
  f2v r;
  r.x = __uint_as_float(d << 16);
  r.y = __uint_as_float(d & 0xFFFF0000u);
  return r;
}
__device__ __forceinline__ f2v mk2(float a, float b) {
  f2v r; r.x = a; r.y = b; return r;
}

#define LSTM11_SHBYTES (65536 + 1024)  // 8x512 uint4 (gates 0,1 bf16) + h ping-pong

template <bool LAST_ONLY>
__global__ __launch_bounds__(512)
__attribute__((amdgpu_waves_per_eu(2, 2)))
void k_lstm11(const float* __restrict__ pre,
              const float* __restrict__ Whh,
              const uint4* __restrict__ wpkA,
              float* __restrict__ yout) {
  extern __shared__ unsigned char smem[];
  uint4* wlds = (uint4*)smem;              // [8][512] uint4 = 64 KB
  float* hb   = (float*)(smem + 65536);    // [2][128] ping-pong
  const int tid = threadIdx.x;
  const int b = blockIdx.x;
  const int c4 = tid & 3;   // k-quarter
  const int u = tid >> 2;   // hidden unit 0..127

  // rotated float4 indices into h (R2-verified conflict-free pattern)
  int hidx[8];
#pragma unroll
  for (int j = 0; j < 8; j++) hidx[j] = c4 * 8 + (((u & 7) + 2 * c4 + j) & 7);

  // stage bf16 weights for gates 0,1 into LDS (once)
#pragma unroll
  for (int c = 0; c < 8; c++) wlds[c * 512 + tid] = wpkA[c * 512 + tid];

  // named f32 weight fragments for gates 2,3 (R7 mechanism)
#define DECLW(g, j) \
  f4v W##g##_##j = *(const f4v*)(Whh + (size_t)((g)*128 + u) * 128 + hidx[j] * 4);
  DECLW(2, 0) DECLW(2, 1) DECLW(2, 2) DECLW(2, 3)
  DECLW(2, 4) DECLW(2, 5) DECLW(2, 6) DECLW(2, 7)
  DECLW(3, 0) DECLW(3, 1) DECLW(3, 2) DECLW(3, 3)
  DECLW(3, 4) DECLW(3, 5) DECLW(3, 6) DECLW(3, 7)
#undef DECLW

  if (tid < 128) hb[tid] = 0.f;
  float cs = 0.f;
  const float* preb = pre + (size_t)b * NT * NG + tid;  // tid == u*4 + c4 == P' column
  float pcur = preb[0];
  float* ybase = LAST_ONLY ? (yout + (size_t)b * NH + u)
                           : (yout + (size_t)b * NT * NH + u);
  __syncthreads();

#define PINW(g) \
  asm volatile("" : "+v"(W##g##_0), "+v"(W##g##_1), "+v"(W##g##_2), "+v"(W##g##_3)); \
  asm volatile("" : "+v"(W##g##_4), "+v"(W##g##_5), "+v"(W##g##_6), "+v"(W##g##_7));

  // bf16 gate from LDS: 4 uint4 chunks, chunk q pairs with h[2q], h[2q+1]
#define GATEL(g, SG)                                                           \
  {                                                                            \
    f2v ag = {0.f, 0.f};                                                       \
    _Pragma("unroll")                                                          \
    for (int q = 0; q < 4; q++) {                                              \
      uint4 wd = wlds[((g) * 4 + q) * 512 + tid];                              \
      f4v ha = hv[2 * q];                                                      \
      f4v hc = hv[2 * q + 1];                                                  \
      ag = __builtin_elementwise_fma(unpk(wd.x), mk2(ha.x, ha.y), ag);         \
      ag = __builtin_elementwise_fma(unpk(wd.y), mk2(ha.z, ha.w), ag);         \
      ag = __builtin_elementwise_fma(unpk(wd.z), mk2(hc.x, hc.y), ag);         \
      ag = __builtin_elementwise_fma(unpk(wd.w), mk2(hc.z, hc.w), ag);         \
    }                                                                          \
    SG = ag.x + ag.y;                                                          \
  }

#define FMA_J(j)                                                               \
  {                                                                            \
    f4v hj = hv[j];                                                            \
    a2 = __builtin_elementwise_fma(W2_##j, hj, a2);                            \
    a3 = __builtin_elementwise_fma(W3_##j, hj, a3);                            \
  }

#define LSTM_STEP(CUR, NXT, T)                                                 \
  {                                                                            \
    int tn = (T) + 1; if (tn > NT - 1) tn = NT - 1;                            \
    float pnext = preb[(size_t)tn * NG];                                       \
    const f4v* hp = (const f4v*)(hb + (CUR) * 128);                            \
    f4v hv[8];                                                                 \
    _Pragma("unroll")                                                          \
    for (int j = 0; j < 8; j++) hv[j] = hp[hidx[j]];                           \
    float s0, s1;                                                              \
    GATEL(0, s0) GATEL(1, s1)                                                  \
    f4v a2 = {0.f, 0.f, 0.f, 0.f}, a3 = a2;                                    \
    FMA_J(0) FMA_J(1) FMA_J(2) FMA_J(3)                                        \
    FMA_J(4) FMA_J(5) FMA_J(6) FMA_J(7)                                        \
    float s2 = (a2.x + a2.y) + (a2.z + a2.w);                                  \
    float s3 = (a3.x + a3.y) + (a3.z + a3.w);                                  \
    s0 += (c4 == 0) ? pcur : 0.f;                                              \
    s1 += (c4 == 1) ? pcur : 0.f;                                              \
    s2 += (c4 == 2) ? pcur : 0.f;                                              \
    s3 += (c4 == 3) ? pcur : 0.f;                                              \
    s0 = dppadd<0xB1>(s0); s0 = dppadd<0x4E>(s0);                              \
    s1 = dppadd<0xB1>(s1); s1 = dppadd<0x4E>(s1);                              \
    s2 = dppadd<0xB1>(s2); s2 = dppadd<0x4E>(s2);                              \
    s3 = dppadd<0xB1>(s3); s3 = dppadd<0x4E>(s3);                              \
    float si = sigf(s0), sf = sigf(s1), tg = tanhf_fast(s2), so = sigf(s3);    \
    cs = sf * cs + si * tg;                                                    \
    float hnew = so * tanhf_fast(cs);                                          \
    if (c4 == 0) hb[(NXT) * 128 + u] = hnew;                                   \
    if (!LAST_ONLY) {                                                          \
      if (c4 == 1) ybase[(size_t)(T) * NH] = hnew;                             \
    } else if ((T) == NT - 1) {                                                \
      if (c4 == 1) *ybase = hnew;                                              \
    }                                                                          \
    pcur = pnext;                                                              \
    __syncthreads();                                                           \
  }

  for (int t = 0; t < NT; t += 2) {
    PINW(2) PINW(3)
    LSTM_STEP(0, 1, t);
    LSTM_STEP(1, 0, t + 1);
  }
#undef LSTM_STEP
#undef FMA_J
#undef GATEL
#undef PINW
}

// ---------------- host ----------------

extern "C" void kernel_launch(void* const* d_in, const int* in_sizes, int n_in,
                              void* d_out, int out_size, void* d_ws, size_t ws_size,
                              hipStream_t stream) {
  const float* x    = (const float*)d_in[0];   // [64,256,64] -> [16384,64]
  const float* dist = (const float*)d_in[1];   // [64,64]
  const int*   ei   = (const int*)d_in[2];     // [2, 524288]
  const float* W0   = (const float*)d_in[3];   // [4160,128]
  const float* b0   = (const float*)d_in[4];
  const float* W1   = (const float*)d_in[5];   // [128,128]
  const float* b1   = (const float*)d_in[6];
  const float* W2   = (const float*)d_in[7];
  const float* b2   = (const float*)d_in[8];
  const float* Wih0 = (const float*)d_in[9];   // [512,128]
  const float* Whh0 = (const float*)d_in[10];  // [512,128]
  const float* bih0 = (const float*)d_in[11];
  const float* bhh0 = (const float*)d_in[12];
  const float* Wih1 = (const float*)d_in[13];
  const float* Whh1 = (const float*)d_in[14];
  const float* bih1 = (const float*)d_in[15];
  const float* bhh1 = (const float*)d_in[16];
  const float* fcW  = (const float*)d_in[17];  // [768,128]
  const float* fcb  = (const float*)d_in[18];
  float* out = (float*)d_out;

  char* ws = (char*)d_ws;
  size_t off = 0;
  auto alloc = [&](size_t bytes) -> void* {
    void* p = ws + off;
    off += (bytes + 255) & ~(size_t)255;
    return p;
  };
  float* bufA     = (float*)alloc((size_t)NN * 128 * 4);
  float* bufB     = (float*)alloc((size_t)NN * 128 * 4);
  float* pre      = (float*)alloc((size_t)NN * 512 * 4);
  int2*  csr      = (int2*)alloc((size_t)NE * 8);
  int*   counts   = (int*)alloc((size_t)NN * 4);
  int*   fillc    = (int*)alloc((size_t)NN * 4);
  int*   rowstart = (int*)alloc((size_t)(NN + 1) * 4);
  float* dinv     = (float*)alloc((size_t)NN * 4);
  float* dvec     = (float*)alloc(128 * 4);
  float* hlast    = (float*)alloc(64 * 128 * 4);
  float* wt0      = (float*)alloc(128 * 64 * 4);
  float* wt1      = (float*)alloc(128 * 128 * 4);
  float* wt2      = (float*)alloc(128 * 128 * 4);
  uint4* wpkA0    = (uint4*)alloc((size_t)4096 * 16);
  uint4* wpkA1    = (uint4*)alloc((size_t)4096 * 16);
  (void)ws_size; (void)in_sizes; (void)n_in; (void)out_size;

  const int* srcIdx = ei;
  const int* dstIdx = ei + NE;

  hipMemsetAsync(counts, 0, (size_t)NN * 4, stream);
  hipMemsetAsync(fillc, 0, (size_t)NN * 4, stream);

  // allow >64KB dynamic LDS for the LSTM kernels (host-side, capture-safe)
  hipFuncSetAttribute(reinterpret_cast<const void*>(&k_lstm11<false>),
                      hipFuncAttributeMaxDynamicSharedMemorySize, LSTM11_SHBYTES);
  hipFuncSetAttribute(reinterpret_cast<const void*>(&k_lstm11<true>),
                      hipFuncAttributeMaxDynamicSharedMemorySize, LSTM11_SHBYTES);

  // weight transposes + distance vector + bf16 packs (gates 0,1)
  k_transpose<<<(64 * 128 + 255) / 256, 256, 0, stream>>>(W0, wt0, 64, 128);
  k_transpose<<<(128 * 128 + 255) / 256, 256, 0, stream>>>(W1, wt1, 128, 128);
  k_transpose<<<(128 * 128 + 255) / 256, 256, 0, stream>>>(W2, wt2, 128, 128);
  k_dvec<<<128, 256, 0, stream>>>(dist, W0, dvec);
  k_packw2<<<16, 256, 0, stream>>>(Whh0, wpkA0);
  k_packw2<<<16, 256, 0, stream>>>(Whh1, wpkA1);

  // CSR build (reused by all 3 GCN layers); dinv fused into scan
  k_count<<<NE / 256, 256, 0, stream>>>(dstIdx, counts);
  k_scan<<<1, 1024, 0, stream>>>(counts, rowstart, dinv);
  k_fill<<<NE / 256, 256, 0, stream>>>(srcIdx, dstIdx, rowstart, fillc, dinv, csr);

  // GCN layer 0: h0 = x @ W0a^T + dvec  (bias/relu happen after aggregation)
  dim3 gH(NN / 64, 128 / 64);
  k_gemm_abt<64, false><<<gH, 256, 0, stream>>>(x, wt0, dvec, nullptr, bufB, 128);
  k_agg<<<NN / 4, 256, 0, stream>>>(bufB, rowstart, csr, dinv, b0, bufA);
  // GCN layer 1
  k_gemm_abt<128, false><<<gH, 256, 0, stream>>>(bufA, wt1, nullptr, nullptr, bufB, 128);
  k_agg<<<NN / 4, 256, 0, stream>>>(bufB, rowstart, csr, dinv, b1, bufA);
  // GCN layer 2
  k_gemm_abt<128, false><<<gH, 256, 0, stream>>>(bufA, wt2, nullptr, nullptr, bufB, 128);
  k_agg<<<NN / 4, 256, 0, stream>>>(bufB, rowstart, csr, dinv, b2, bufA);

  // LSTM layer 0: pre (permuted) = feat @ Wih0^T + bih0 + bhh0 ; recurrence -> y1 (bufB)
  dim3 gP(NN / 64, 512 / 64);
  k_gemm_abt<128, false, true><<<gP, 256, 0, stream>>>(bufA, Wih0, bih0, bhh0, pre, 512);
  k_lstm11<false><<<64, 512, LSTM11_SHBYTES, stream>>>(pre, Whh0, wpkA0, bufB);
  // LSTM layer 1
  k_gemm_abt<128, false, true><<<gP, 256, 0, stream>>>(bufB, Wih1, bih1, bhh1, pre, 512);
  k_lstm11<true><<<64, 512, LSTM11_SHBYTES, stream>>>(pre, Whh1, wpkA1, hlast);

  // FC: out[64,768] = hlast @ fcW^T + fcb
  dim3 gF(1, NOUT / 64);
  k_gemm_abt<128, false><<<gF, 256, 0, stream>>>(hlast, fcW, fcb, nullptr, out, NOUT);
}